// Round 12
// baseline (260.894 us; speedup 1.0000x reference)
//
#include <hip/hip_runtime.h>
#include <stdint.h>

typedef __bf16 bf16x8 __attribute__((ext_vector_type(8)));
typedef float  f32x4  __attribute__((ext_vector_type(4)));
typedef float  f32x16 __attribute__((ext_vector_type(16)));
typedef unsigned short u16;
typedef unsigned int u32;
typedef u16 u16x8 __attribute__((ext_vector_type(8)));
typedef u32 u32x4 __attribute__((ext_vector_type(4)));

__device__ __forceinline__ u16 f2bf(float f) {
  uint32_t u = __builtin_bit_cast(uint32_t, f);
  u += 0x7fffu + ((u >> 16) & 1u);
  return (u16)(u >> 16);
}
__device__ __forceinline__ u32 cvtpk(float lo, float hi) {
  u32 r;
  asm("v_cvt_pk_bf16_f32 %0, %1, %2" : "=v"(r) : "v"(lo), "v"(hi));
  return r;
}
__device__ __forceinline__ float fexp2(float x) {   // raw v_exp_f32 (exp2); -inf -> 0
  float r;
  asm("v_exp_f32 %0, %1" : "=v"(r) : "v"(x));
  return r;
}

// async global->LDS, 16B per lane; lds base is wave-uniform (lane writes at +lane*16B)
__device__ __forceinline__ void async_cp16(const void* src, void* lds) {
  __builtin_amdgcn_global_load_lds(
      (const __attribute__((address_space(1))) uint32_t*)src,
      (__attribute__((address_space(3))) uint32_t*)lds, 16, 0, 0);
}

// ---------------- fused fp32 -> bf16 converts ----------------
struct CvtArgs {
  const float* in[8];
  u16* out[8];
  int n8[8];
  int nblk[8];
};
__global__ void cvt_multi(CvtArgs a) {
  int bx = blockIdx.x;
  int t = 0;
  while (t < 7 && bx >= a.nblk[t]) { bx -= a.nblk[t]; ++t; }
  const int i = bx * 256 + threadIdx.x;
  if (i >= a.n8[t]) return;
  const float4* p = (const float4*)a.in[t] + (size_t)i * 2;
  float4 va = p[0], vb = p[1];
  u16x8 r;
  r[0] = f2bf(va.x); r[1] = f2bf(va.y); r[2] = f2bf(va.z); r[3] = f2bf(va.w);
  r[4] = f2bf(vb.x); r[5] = f2bf(vb.y); r[6] = f2bf(vb.z); r[7] = f2bf(vb.w);
  ((u16x8*)a.out[t])[i] = r;
}

// ------- batched GEMM: C = A[M,K] * Bw[N,K]^T, BK=64, 2-phase dbuf ---------
struct GemmB3 {
  const u16* A[3];
  const u16* Bm[3];
  u16* C[3];
  float alpha[3];
  int Nz[3];
};

template<bool F32OUT>
__global__ __launch_bounds__(256, 2)
void gemm_bt(GemmB3 args, float* __restrict__ Cf, const float* __restrict__ bias,
             int K, int zswap)
{
  __shared__ u16 At[2][128 * 64];
  __shared__ u16 Bt[2][128 * 64];
  const int z = blockIdx.z;
  const u16* __restrict__ A  = args.A[z];
  const u16* __restrict__ Bw = args.Bm[z];
  const int N = args.Nz[z];
  int bx = blockIdx.x, by = blockIdx.y;
  if (z == zswap) { const int t = bx; bx = by; by = t; }
  const int bm = bx * 128;
  const int bn = by * 128;
  const int tid = threadIdx.x;
  const int w  = tid >> 6;
  const int l  = tid & 63;
  const int lr = l & 15;
  const int lg = l >> 4;
  const int wr = (w >> 1) * 64;
  const int wc = (w & 1) * 64;

  f32x4 acc[4][4];
  #pragma unroll
  for (int m = 0; m < 4; ++m)
    #pragma unroll
    for (int n = 0; n < 4; ++n) acc[m][n] = (f32x4){0.f, 0.f, 0.f, 0.f};

  auto stage = [&](int buf, int k0) {
    #pragma unroll
    for (int i = 0; i < 4; ++i) {
      const int slot = i * 256 + tid;
      const int row  = slot >> 3;      // 0..127
      const int pos  = slot & 7;
      const int gs   = pos ^ (row & 7);
      async_cp16(A  + (size_t)(bm + row) * K + k0 + gs * 8,
                 &At[buf][(i * 256 + w * 64) * 8]);
      async_cp16(Bw + (size_t)(bn + row) * K + k0 + gs * 8,
                 &Bt[buf][(i * 256 + w * 64) * 8]);
    }
  };

  const int nk = K >> 6;
  stage(0, 0);
  int cur = 0;

  for (int t = 0; t < nk; ++t) {
    __syncthreads();                       // drains stage of tile t
    if (t + 1 < nk) stage(cur ^ 1, (t + 1) * 64);
    #pragma unroll
    for (int kk = 0; kk < 2; ++kk) {
      bf16x8 af[4], bfr[4];
      #pragma unroll
      for (int m = 0; m < 4; ++m) {
        const int row = wr + m * 16 + lr;
        const int pos = (kk * 4 + lg) ^ (row & 7);
        af[m] = *(const bf16x8*)(&At[cur][row * 64 + pos * 8]);
      }
      #pragma unroll
      for (int n = 0; n < 4; ++n) {
        const int row = wc + n * 16 + lr;
        const int pos = (kk * 4 + lg) ^ (row & 7);
        bfr[n] = *(const bf16x8*)(&Bt[cur][row * 64 + pos * 8]);
      }
      __builtin_amdgcn_s_setprio(1);
      #pragma unroll
      for (int m = 0; m < 4; ++m)
        #pragma unroll
        for (int n = 0; n < 4; ++n)
          acc[m][n] = __builtin_amdgcn_mfma_f32_16x16x32_bf16(af[m], bfr[n], acc[m][n], 0, 0, 0);
      __builtin_amdgcn_s_setprio(0);
    }
    cur ^= 1;
  }

  if constexpr (F32OUT) {
    #pragma unroll
    for (int n = 0; n < 4; ++n) {
      const int col = bn + wc + n * 16 + lr;
      const float bv = bias[col];
      #pragma unroll
      for (int m = 0; m < 4; ++m) {
        const int rbase = bm + wr + m * 16 + lg * 4;
        #pragma unroll
        for (int j = 0; j < 4; ++j)
          Cf[(size_t)(rbase + j) * N + col] = acc[m][n][j] + bv;
      }
    }
  } else {
    u16* __restrict__ C = args.C[z];
    const float alpha = args.alpha[z];
    #pragma unroll
    for (int n = 0; n < 4; ++n) {
      const int col = bn + wc + n * 16 + lr;
      #pragma unroll
      for (int m = 0; m < 4; ++m) {
        const int rbase = bm + wr + m * 16 + lg * 4;
        #pragma unroll
        for (int j = 0; j < 4; ++j)
          C[(size_t)(rbase + j) * N + col] = f2bf(acc[m][n][j] * alpha);
      }
    }
  }
}

// ---------------- flash attention, swapped 32x32 ----------------------------
// QBLK=128, 4 waves, SBLK=64. K staged in LDS (dbuf, XOR swizzle); V fragments
// read DIRECTLY from global Vtg (L2-resident, lane-contiguous 16B).
// Lane (ql,hi) V-frag addr: Vp + (dt*32+ql)*4096 + s0 + (2*ks+hi)*8
//   = vA + dt*32*4096 + s0 + ks*16, with vA = Vp + ql*4096 + hi*8.
__global__ __launch_bounds__(256, 2)
void mla_attn(const u16* __restrict__ Qu, const u16* __restrict__ Ku,
              const u16* __restrict__ Vtg, u16* __restrict__ ctx)
{
  __shared__ u16 Ktb[2][64 * 128];   // [s][dh granules], pos g holds granule g^(s&15)

  const int bid = blockIdx.x;
  const int kk  = bid >> 5;
  const int qt  = 2 * (kk & 7) + (kk >> 3);   // pairs (kk,kk+8) -> adjacent qt
  const int bh  = bid & 31;
  const int b = bh >> 4, h = bh & 15;
  const int qbase = qt * 128;
  const int tid = threadIdx.x;
  const int w = tid >> 6, l = tid & 63;
  const int ql = l & 31;
  const int hi = l >> 5;
  const bool hb = (hi != 0);
  const int T = 2048;
  const size_t rs = 2048;

  const u16* Qp = Qu + ((size_t)b * T) * rs + (size_t)h * 128;
  const u16* Kp = Ku + ((size_t)b * T) * rs + (size_t)h * 128;
  const u16* Vp = Vtg + (size_t)(h * 128) * 4096 + (size_t)b * T;

  const int qw = qbase + w * 32;
  const int qg = qw + ql;

  bf16x8 qf[8];
  #pragma unroll
  for (int kb = 0; kb < 8; ++kb)
    qf[kb] = *(const bf16x8*)(Qp + (size_t)qg * rs + kb * 16 + hi * 8);

  // per-lane direct-global V base (hi baked in; add dt*32*4096 + s0 + ks*16)
  const u16* vA = Vp + (size_t)ql * 4096 + hi * 8;

  f32x16 acc[4];
  #pragma unroll
  for (int dt = 0; dt < 4; ++dt)
    #pragma unroll
    for (int r = 0; r < 16; ++r) acc[dt][r] = 0.f;
  float mrun = -1.0e30f, lsum = 0.f;

  const int ksr = tid >> 4;
  const u16* kb0 = Kp + (size_t)ksr * rs + (((tid & 15) ^ (ksr & 15)) * 8);

  const int nT = 2 * qt + 2;

  auto stage = [&](int buf, int it) {
    const int s0 = it * 64;
    #pragma unroll
    for (int i = 0; i < 4; ++i)
      async_cp16(kb0 + (size_t)(s0 + i * 16) * rs, &Ktb[buf][(i * 256 + w * 64) * 8]);
  };

  stage(0, 0);
  int cur = 0;

  for (int it = 0; it < nT; ++it) {
    __syncthreads();
    if (it + 1 < nT) stage(cur ^ 1, it + 1);
    const int s0 = it * 64;
    if (s0 <= qw + 31) {
      const u16* Kt = Ktb[cur];
      const bool diag = (it == (qw >> 6));

      f32x16 c0, c1;
      #pragma unroll
      for (int r = 0; r < 16; ++r) { c0[r] = 0.f; c1[r] = 0.f; }
      __builtin_amdgcn_s_setprio(1);
      #pragma unroll
      for (int kb = 0; kb < 8; ++kb) {
        bf16x8 kf0 = *(const bf16x8*)(Kt + ql * 128 + (((2 * kb + hi) ^ (ql & 15)) * 8));
        c0 = __builtin_amdgcn_mfma_f32_32x32x16_bf16(kf0, qf[kb], c0, 0, 0, 0);
      }
      #pragma unroll
      for (int kb = 0; kb < 8; ++kb) {
        bf16x8 kf1 = *(const bf16x8*)(Kt + (32 + ql) * 128 + (((2 * kb + hi) ^ (ql & 15)) * 8));
        c1 = __builtin_amdgcn_mfma_f32_32x32x16_bf16(kf1, qf[kb], c1, 0, 0, 0);
      }
      __builtin_amdgcn_s_setprio(0);

      // issue V loads now; L2 latency hides under softmax/pack below
      bf16x8 vfr[4][4];
      #pragma unroll
      for (int dt = 0; dt < 4; ++dt)
        #pragma unroll
        for (int ks = 0; ks < 4; ++ks)
          vfr[dt][ks] = *(const bf16x8*)(vA + (size_t)(dt * 32) * 4096 + s0 + ks * 16);

      float p[32];
      if (diag) {
        #pragma unroll
        for (int r = 0; r < 16; ++r) {
          const int sg0 = s0 + 4 * hi + (r & 3) + 8 * (r >> 2);
          p[r]      = (sg0      <= qg) ? c0[r] : -INFINITY;
          p[16 + r] = (sg0 + 32 <= qg) ? c1[r] : -INFINITY;
        }
      } else {
        #pragma unroll
        for (int r = 0; r < 16; ++r) { p[r] = c0[r]; p[16 + r] = c1[r]; }
      }
      float t16[16];
      #pragma unroll
      for (int r = 0; r < 16; ++r) t16[r] = fmaxf(p[r], p[16 + r]);
      float t8[8];
      #pragma unroll
      for (int r = 0; r < 8; ++r) t8[r] = fmaxf(t16[r], t16[8 + r]);
      float t4[4];
      #pragma unroll
      for (int r = 0; r < 4; ++r) t4[r] = fmaxf(t8[r], t8[4 + r]);
      float mx = fmaxf(fmaxf(t4[0], t4[1]), fmaxf(t4[2], t4[3]));
      mx = fmaxf(mx, __shfl_xor(mx, 32));
      if (__any(mx > mrun + 8.f)) {
        const float mnew = fmaxf(mrun, mx);
        const float scl = fexp2(mrun - mnew);
        mrun = mnew;
        lsum *= scl;
        #pragma unroll
        for (int dt = 0; dt < 4; ++dt)
          #pragma unroll
          for (int r = 0; r < 16; ++r) acc[dt][r] *= scl;
      }
      #pragma unroll
      for (int r = 0; r < 32; ++r) p[r] = fexp2(p[r] - mrun);
      float s16[16];
      #pragma unroll
      for (int r = 0; r < 16; ++r) s16[r] = p[r] + p[16 + r];
      float s8[8];
      #pragma unroll
      for (int r = 0; r < 8; ++r) s8[r] = s16[r] + s16[8 + r];
      float s4[4];
      #pragma unroll
      for (int r = 0; r < 4; ++r) s4[r] = s8[r] + s8[4 + r];
      float psum = (s4[0] + s4[1]) + (s4[2] + s4[3]);
      lsum += psum + __shfl_xor(psum, 32);

      bf16x8 fr[4];
      #pragma unroll
      for (int st = 0; st < 2; ++st) {
        const int o = st * 16;
        u32 P0 = cvtpk(p[o + 0], p[o + 1]),   P1 = cvtpk(p[o + 2], p[o + 3]);
        u32 P2 = cvtpk(p[o + 4], p[o + 5]),   P3 = cvtpk(p[o + 6], p[o + 7]);
        u32 P4 = cvtpk(p[o + 8], p[o + 9]),   P5 = cvtpk(p[o + 10], p[o + 11]);
        u32 P6 = cvtpk(p[o + 12], p[o + 13]), P7 = cvtpk(p[o + 14], p[o + 15]);
        u32 Y0 = __shfl_xor(hb ? P0 : P2, 32);
        u32 Y1 = __shfl_xor(hb ? P1 : P3, 32);
        u32 Y2 = __shfl_xor(hb ? P4 : P6, 32);
        u32 Y3 = __shfl_xor(hb ? P5 : P7, 32);
        fr[st * 2 + 0] = __builtin_bit_cast(bf16x8,
            (u32x4){hb ? Y0 : P0, hb ? Y1 : P1, hb ? P2 : Y0, hb ? P3 : Y1});
        fr[st * 2 + 1] = __builtin_bit_cast(bf16x8,
            (u32x4){hb ? Y2 : P4, hb ? Y3 : P5, hb ? P6 : Y2, hb ? P7 : Y3});
      }

      __builtin_amdgcn_s_setprio(1);
      #pragma unroll
      for (int dt = 0; dt < 4; ++dt) {
        #pragma unroll
        for (int ks = 0; ks < 4; ++ks)
          acc[dt] = __builtin_amdgcn_mfma_f32_32x32x16_bf16(vfr[dt][ks], fr[ks], acc[dt], 0, 0, 0);
      }
      __builtin_amdgcn_s_setprio(0);
    }
    cur ^= 1;
  }

  __syncthreads();
  u16* Ot = &Ktb[0][0];   // 128x128 u16 = 32KB (both K buffers)
  const float inv = 1.f / lsum;
  const int orow = w * 32 + ql;
  #pragma unroll
  for (int dt = 0; dt < 4; ++dt) {
    #pragma unroll
    for (int rq = 0; rq < 4; ++rq) {
      const int dhb = dt * 32 + 8 * rq + 4 * hi;
      const int dhs = dhb ^ ((ql & 15) << 3);
      u16 e0 = f2bf(acc[dt][rq * 4 + 0] * inv);
      u16 e1 = f2bf(acc[dt][rq * 4 + 1] * inv);
      u16 e2 = f2bf(acc[dt][rq * 4 + 2] * inv);
      u16 e3 = f2bf(acc[dt][rq * 4 + 3] * inv);
      u32 w0 = (u32)e0 | ((u32)e1 << 16);
      u32 w1 = (u32)e2 | ((u32)e3 << 16);
      *(u32*)(Ot + orow * 128 + dhs)     = w0;
      *(u32*)(Ot + orow * 128 + dhs + 2) = w1;
    }
  }
  __syncthreads();
  #pragma unroll
  for (int i = 0; i < 8; ++i) {
    const int n = i * 256 + tid;
    const int q = n >> 4, g = n & 15;
    bf16x8 v = *(const bf16x8*)(Ot + q * 128 + ((g ^ (q & 15)) * 8));
    *(bf16x8*)(ctx + ((size_t)b * T + qbase + q) * rs + h * 128 + g * 8) = v;
  }
}

// ---------------- launcher ----------------
extern "C" void kernel_launch(void* const* d_in, const int* in_sizes, int n_in,
                              void* d_out, int out_size, void* d_ws, size_t ws_size,
                              hipStream_t stream)
{
  (void)n_in; (void)out_size; (void)ws_size;
  const float* x   = (const float*)d_in[0];
  const float* qdw = (const float*)d_in[1];
  const float* kdw = (const float*)d_in[2];
  const float* vdw = (const float*)d_in[3];
  const float* quw = (const float*)d_in[4];
  const float* kuw = (const float*)d_in[5];
  const float* vuw = (const float*)d_in[6];
  const float* oww = (const float*)d_in[7];
  const float* ob  = (const float*)d_in[8];

  const int d = 2048, r = 512;
  const int BT = in_sizes[0] / d;   // B*T = 4096

  u16* p = (u16*)d_ws;
  auto take = [&](size_t n) { u16* q = p; p += n; return q; };
  u16* xb  = take((size_t)BT * d);
  u16* wqd = take((size_t)r * d);
  u16* wkd = take((size_t)r * d);
  u16* wvd = take((size_t)r * d);
  u16* wqu = take((size_t)d * r);
  u16* wku = take((size_t)d * r);
  u16* wvu = take((size_t)d * r);
  u16* wow = take((size_t)d * d);
  u16* Qd  = take((size_t)BT * r);
  u16* Kd  = take((size_t)BT * r);
  u16* Vd  = take((size_t)BT * r);
  u16* Qu  = take((size_t)BT * d);
  u16* Ku  = take((size_t)BT * d);
  u16* Vtg = take((size_t)BT * d);   // transposed: [d][BT]
  u16* ctx = take((size_t)BT * d);

  CvtArgs ca;
  const float* ins[8] = {x, oww, qdw, kdw, vdw, quw, kuw, vuw};
  u16* outs[8]        = {xb, wow, wqd, wkd, wvd, wqu, wku, wvu};
  const size_t ns[8]  = {(size_t)BT * d, (size_t)d * d,
                         (size_t)r * d, (size_t)r * d, (size_t)r * d,
                         (size_t)d * r, (size_t)d * r, (size_t)d * r};
  int total_blk = 0;
  for (int t = 0; t < 8; ++t) {
    ca.in[t] = ins[t]; ca.out[t] = outs[t];
    ca.n8[t] = (int)(ns[t] / 8);
    ca.nblk[t] = (ca.n8[t] + 255) / 256;
    total_blk += ca.nblk[t];
  }
  cvt_multi<<<dim3(total_blk), dim3(256), 0, stream>>>(ca);

  // down projections: Qd/Kd/Vd = x @ Wd^T   [BT,2048] -> [BT,512]
  GemmB3 g1;
  g1.A[0] = xb;  g1.A[1] = xb;  g1.A[2] = xb;
  g1.Bm[0] = wqd; g1.Bm[1] = wkd; g1.Bm[2] = wvd;
  g1.C[0] = Qd;  g1.C[1] = Kd;  g1.C[2] = Vd;
  g1.alpha[0] = 1.f; g1.alpha[1] = 1.f; g1.alpha[2] = 1.f;
  g1.Nz[0] = r; g1.Nz[1] = r; g1.Nz[2] = r;
  gemm_bt<false><<<dim3(BT / 128, r / 128, 3), dim3(256), 0, stream>>>(
      g1, nullptr, nullptr, d, -1);

  // up projections, one launch: z0=Qu, z1=Ku, z2=Vtg (transposed, swapped grid)
  GemmB3 g2;
  g2.A[0] = Qd;  g2.A[1] = Kd;  g2.A[2] = wvu;
  g2.Bm[0] = wqu; g2.Bm[1] = wku; g2.Bm[2] = Vd;
  g2.C[0] = Qu;  g2.C[1] = Ku;  g2.C[2] = Vtg;
  g2.alpha[0] = 0.12751743f; g2.alpha[1] = 1.f; g2.alpha[2] = 1.f;
  g2.Nz[0] = d; g2.Nz[1] = d; g2.Nz[2] = BT;
  gemm_bt<false><<<dim3(BT / 128, d / 128, 3), dim3(256), 0, stream>>>(
      g2, nullptr, nullptr, r, 2);

  // flash attention: 16 q-tiles x 32 (b,h)
  mla_attn<<<dim3(512), dim3(256), 0, stream>>>(Qu, Ku, Vtg, ctx);

  // output projection: out = ctx @ out_w^T + out_b (fp32 out)
  GemmB3 g3;
  g3.A[0] = ctx; g3.A[1] = ctx; g3.A[2] = ctx;
  g3.Bm[0] = wow; g3.Bm[1] = wow; g3.Bm[2] = wow;
  g3.C[0] = nullptr; g3.C[1] = nullptr; g3.C[2] = nullptr;
  g3.alpha[0] = 1.f; g3.alpha[1] = 1.f; g3.alpha[2] = 1.f;
  g3.Nz[0] = d; g3.Nz[1] = d; g3.Nz[2] = d;
  gemm_bt<true><<<dim3(BT / 128, d / 128, 1), dim3(256), 0, stream>>>(
      g3, (float*)d_out, ob, d, -1);
}

// Round 13
// 198.728 us; speedup vs baseline: 1.3128x; 1.3128x over previous
//
#include <hip/hip_runtime.h>
#include <stdint.h>

typedef __bf16 bf16x8 __attribute__((ext_vector_type(8)));
typedef float  f32x4  __attribute__((ext_vector_type(4)));
typedef float  f32x16 __attribute__((ext_vector_type(16)));
typedef unsigned short u16;
typedef unsigned int u32;
typedef u16 u16x8 __attribute__((ext_vector_type(8)));
typedef u32 u32x4 __attribute__((ext_vector_type(4)));

__device__ __forceinline__ u16 f2bf(float f) {
  uint32_t u = __builtin_bit_cast(uint32_t, f);
  u += 0x7fffu + ((u >> 16) & 1u);
  return (u16)(u >> 16);
}
__device__ __forceinline__ u32 cvtpk(float lo, float hi) {
  u32 r;
  asm("v_cvt_pk_bf16_f32 %0, %1, %2" : "=v"(r) : "v"(lo), "v"(hi));
  return r;
}
__device__ __forceinline__ float fexp2(float x) {   // raw v_exp_f32 (exp2); -inf -> 0
  float r;
  asm("v_exp_f32 %0, %1" : "=v"(r) : "v"(x));
  return r;
}

// async global->LDS, 16B per lane; lds base is wave-uniform (lane writes at +lane*16B)
__device__ __forceinline__ void async_cp16(const void* src, void* lds) {
  __builtin_amdgcn_global_load_lds(
      (const __attribute__((address_space(1))) uint32_t*)src,
      (__attribute__((address_space(3))) uint32_t*)lds, 16, 0, 0);
}

// ---------------- fused fp32 -> bf16 converts ----------------
struct CvtArgs {
  const float* in[8];
  u16* out[8];
  int n8[8];
  int nblk[8];
};
__global__ void cvt_multi(CvtArgs a) {
  int bx = blockIdx.x;
  int t = 0;
  while (t < 7 && bx >= a.nblk[t]) { bx -= a.nblk[t]; ++t; }
  const int i = bx * 256 + threadIdx.x;
  if (i >= a.n8[t]) return;
  const float4* p = (const float4*)a.in[t] + (size_t)i * 2;
  float4 va = p[0], vb = p[1];
  u16x8 r;
  r[0] = f2bf(va.x); r[1] = f2bf(va.y); r[2] = f2bf(va.z); r[3] = f2bf(va.w);
  r[4] = f2bf(vb.x); r[5] = f2bf(vb.y); r[6] = f2bf(vb.z); r[7] = f2bf(vb.w);
  ((u16x8*)a.out[t])[i] = r;
}

// ------- batched GEMM: C = A[M,K] * Bw[N,K]^T, BK=64, 2-phase dbuf ---------
struct GemmB3 {
  const u16* A[3];
  const u16* Bm[3];
  u16* C[3];
  float alpha[3];
  int Nz[3];
};

template<bool F32OUT>
__global__ __launch_bounds__(256, 2)
void gemm_bt(GemmB3 args, float* __restrict__ Cf, const float* __restrict__ bias,
             int K, int zswap)
{
  __shared__ u16 At[2][128 * 64];
  __shared__ u16 Bt[2][128 * 64];
  const int z = blockIdx.z;
  const u16* __restrict__ A  = args.A[z];
  const u16* __restrict__ Bw = args.Bm[z];
  const int N = args.Nz[z];
  int bx = blockIdx.x, by = blockIdx.y;
  if (z == zswap) { const int t = bx; bx = by; by = t; }
  const int bm = bx * 128;
  const int bn = by * 128;
  const int tid = threadIdx.x;
  const int w  = tid >> 6;
  const int l  = tid & 63;
  const int lr = l & 15;
  const int lg = l >> 4;
  const int wr = (w >> 1) * 64;
  const int wc = (w & 1) * 64;

  f32x4 acc[4][4];
  #pragma unroll
  for (int m = 0; m < 4; ++m)
    #pragma unroll
    for (int n = 0; n < 4; ++n) acc[m][n] = (f32x4){0.f, 0.f, 0.f, 0.f};

  auto stage = [&](int buf, int k0) {
    #pragma unroll
    for (int i = 0; i < 4; ++i) {
      const int slot = i * 256 + tid;
      const int row  = slot >> 3;      // 0..127
      const int pos  = slot & 7;
      const int gs   = pos ^ (row & 7);
      async_cp16(A  + (size_t)(bm + row) * K + k0 + gs * 8,
                 &At[buf][(i * 256 + w * 64) * 8]);
      async_cp16(Bw + (size_t)(bn + row) * K + k0 + gs * 8,
                 &Bt[buf][(i * 256 + w * 64) * 8]);
    }
  };

  const int nk = K >> 6;
  stage(0, 0);
  int cur = 0;

  for (int t = 0; t < nk; ++t) {
    __syncthreads();                       // drains stage of tile t
    if (t + 1 < nk) stage(cur ^ 1, (t + 1) * 64);
    #pragma unroll
    for (int kk = 0; kk < 2; ++kk) {
      bf16x8 af[4], bfr[4];
      #pragma unroll
      for (int m = 0; m < 4; ++m) {
        const int row = wr + m * 16 + lr;
        const int pos = (kk * 4 + lg) ^ (row & 7);
        af[m] = *(const bf16x8*)(&At[cur][row * 64 + pos * 8]);
      }
      #pragma unroll
      for (int n = 0; n < 4; ++n) {
        const int row = wc + n * 16 + lr;
        const int pos = (kk * 4 + lg) ^ (row & 7);
        bfr[n] = *(const bf16x8*)(&Bt[cur][row * 64 + pos * 8]);
      }
      __builtin_amdgcn_s_setprio(1);
      #pragma unroll
      for (int m = 0; m < 4; ++m)
        #pragma unroll
        for (int n = 0; n < 4; ++n)
          acc[m][n] = __builtin_amdgcn_mfma_f32_16x16x32_bf16(af[m], bfr[n], acc[m][n], 0, 0, 0);
      __builtin_amdgcn_s_setprio(0);
    }
    cur ^= 1;
  }

  if constexpr (F32OUT) {
    #pragma unroll
    for (int n = 0; n < 4; ++n) {
      const int col = bn + wc + n * 16 + lr;
      const float bv = bias[col];
      #pragma unroll
      for (int m = 0; m < 4; ++m) {
        const int rbase = bm + wr + m * 16 + lg * 4;
        #pragma unroll
        for (int j = 0; j < 4; ++j)
          Cf[(size_t)(rbase + j) * N + col] = acc[m][n][j] + bv;
      }
    }
  } else {
    u16* __restrict__ C = args.C[z];
    const float alpha = args.alpha[z];
    #pragma unroll
    for (int n = 0; n < 4; ++n) {
      const int col = bn + wc + n * 16 + lr;
      #pragma unroll
      for (int m = 0; m < 4; ++m) {
        const int rbase = bm + wr + m * 16 + lg * 4;
        #pragma unroll
        for (int j = 0; j < 4; ++j)
          C[(size_t)(rbase + j) * N + col] = f2bf(acc[m][n][j] * alpha);
      }
    }
  }
}

// ---------------- flash attention, swapped 32x32 (round-10 verified body) ----
// QBLK=128, 4 waves, SBLK=64, K+V LDS dbuf. NEW: pairing in the LOW bid bit —
// under consecutive-bid co-residency every CU pair sums to 36 iter-units
// (qt=e and 15-e share a CU and the same bh's K/V in L2).
__global__ __launch_bounds__(256, 2)
void mla_attn(const u16* __restrict__ Qu, const u16* __restrict__ Ku,
              const u16* __restrict__ Vtg, u16* __restrict__ ctx)
{
  __shared__ u16 Ktb[2][64 * 128];   // [s][dh granules], pos g holds granule g^(s&15)
  __shared__ u16 Vtb[2][128 * 64];   // [dh][s granules], pos g holds granule g^(dh&7)

  const int bid = blockIdx.x;
  const int j   = bid >> 1;
  const int par = bid & 1;
  const int bh  = j & 31;            // adjacent bids share bh (K/V L2 reuse)
  const int e   = j >> 5;            // 0..7
  const int qt  = par ? (15 - e) : e;  // pair (2j,2j+1) -> (e, 15-e): 36 units
  const int b = bh >> 4, h = bh & 15;
  const int qbase = qt * 128;
  const int tid = threadIdx.x;
  const int w = tid >> 6, l = tid & 63;
  const int ql = l & 31;
  const int hi = l >> 5;
  const bool hb = (hi != 0);
  const int T = 2048;
  const size_t rs = 2048;

  const u16* Qp = Qu + ((size_t)b * T) * rs + (size_t)h * 128;
  const u16* Kp = Ku + ((size_t)b * T) * rs + (size_t)h * 128;
  const u16* Vp = Vtg + (size_t)(h * 128) * 4096 + (size_t)b * T;

  const int qw = qbase + w * 32;
  const int qg = qw + ql;

  bf16x8 qf[8];
  #pragma unroll
  for (int kb = 0; kb < 8; ++kb)
    qf[kb] = *(const bf16x8*)(Qp + (size_t)qg * rs + kb * 16 + hi * 8);

  f32x16 acc[4];
  #pragma unroll
  for (int dt = 0; dt < 4; ++dt)
    #pragma unroll
    for (int r = 0; r < 16; ++r) acc[dt][r] = 0.f;
  float mrun = -1.0e30f, lsum = 0.f;

  const int ksr = tid >> 4;
  const u16* kb0 = Kp + (size_t)ksr * rs + (((tid & 15) ^ (ksr & 15)) * 8);
  const int vsr = tid >> 3;
  const u16* vb0 = Vp + (size_t)vsr * 4096 + (((tid & 7) ^ (vsr & 7)) * 8);

  const int nT = 2 * qt + 2;

  auto stage = [&](int buf, int it) {
    const int s0 = it * 64;
    #pragma unroll
    for (int i = 0; i < 4; ++i)
      async_cp16(kb0 + (size_t)(s0 + i * 16) * rs, &Ktb[buf][(i * 256 + w * 64) * 8]);
    #pragma unroll
    for (int i = 0; i < 4; ++i)
      async_cp16(vb0 + (size_t)(i * 32) * 4096 + s0, &Vtb[buf][(i * 256 + w * 64) * 8]);
  };

  stage(0, 0);
  int cur = 0;

  for (int it = 0; it < nT; ++it) {
    __syncthreads();
    if (it + 1 < nT) stage(cur ^ 1, it + 1);
    const int s0 = it * 64;
    if (s0 <= qw + 31) {
      const u16* Kt = Ktb[cur];
      const u16* Vt = Vtb[cur];
      const bool diag = (it == (qw >> 6));

      f32x16 c0, c1;
      #pragma unroll
      for (int r = 0; r < 16; ++r) { c0[r] = 0.f; c1[r] = 0.f; }
      __builtin_amdgcn_s_setprio(1);
      #pragma unroll
      for (int kb = 0; kb < 8; ++kb) {
        bf16x8 kf0 = *(const bf16x8*)(Kt + ql * 128 + (((2 * kb + hi) ^ (ql & 15)) * 8));
        c0 = __builtin_amdgcn_mfma_f32_32x32x16_bf16(kf0, qf[kb], c0, 0, 0, 0);
      }
      #pragma unroll
      for (int kb = 0; kb < 8; ++kb) {
        bf16x8 kf1 = *(const bf16x8*)(Kt + (32 + ql) * 128 + (((2 * kb + hi) ^ (ql & 15)) * 8));
        c1 = __builtin_amdgcn_mfma_f32_32x32x16_bf16(kf1, qf[kb], c1, 0, 0, 0);
      }
      __builtin_amdgcn_s_setprio(0);

      float p[32];
      if (diag) {
        #pragma unroll
        for (int r = 0; r < 16; ++r) {
          const int sg0 = s0 + 4 * hi + (r & 3) + 8 * (r >> 2);
          p[r]      = (sg0      <= qg) ? c0[r] : -INFINITY;
          p[16 + r] = (sg0 + 32 <= qg) ? c1[r] : -INFINITY;
        }
      } else {
        #pragma unroll
        for (int r = 0; r < 16; ++r) { p[r] = c0[r]; p[16 + r] = c1[r]; }
      }
      float t16[16];
      #pragma unroll
      for (int r = 0; r < 16; ++r) t16[r] = fmaxf(p[r], p[16 + r]);
      float t8[8];
      #pragma unroll
      for (int r = 0; r < 8; ++r) t8[r] = fmaxf(t16[r], t16[8 + r]);
      float t4[4];
      #pragma unroll
      for (int r = 0; r < 4; ++r) t4[r] = fmaxf(t8[r], t8[4 + r]);
      float mx = fmaxf(fmaxf(t4[0], t4[1]), fmaxf(t4[2], t4[3]));
      mx = fmaxf(mx, __shfl_xor(mx, 32));
      if (__any(mx > mrun + 8.f)) {
        const float mnew = fmaxf(mrun, mx);
        const float scl = fexp2(mrun - mnew);
        mrun = mnew;
        lsum *= scl;
        #pragma unroll
        for (int dt = 0; dt < 4; ++dt)
          #pragma unroll
          for (int r = 0; r < 16; ++r) acc[dt][r] *= scl;
      }
      #pragma unroll
      for (int r = 0; r < 32; ++r) p[r] = fexp2(p[r] - mrun);
      float s16[16];
      #pragma unroll
      for (int r = 0; r < 16; ++r) s16[r] = p[r] + p[16 + r];
      float s8[8];
      #pragma unroll
      for (int r = 0; r < 8; ++r) s8[r] = s16[r] + s16[8 + r];
      float s4[4];
      #pragma unroll
      for (int r = 0; r < 4; ++r) s4[r] = s8[r] + s8[4 + r];
      float psum = (s4[0] + s4[1]) + (s4[2] + s4[3]);
      lsum += psum + __shfl_xor(psum, 32);

      bf16x8 fr[4];
      #pragma unroll
      for (int st = 0; st < 2; ++st) {
        const int o = st * 16;
        u32 P0 = cvtpk(p[o + 0], p[o + 1]),   P1 = cvtpk(p[o + 2], p[o + 3]);
        u32 P2 = cvtpk(p[o + 4], p[o + 5]),   P3 = cvtpk(p[o + 6], p[o + 7]);
        u32 P4 = cvtpk(p[o + 8], p[o + 9]),   P5 = cvtpk(p[o + 10], p[o + 11]);
        u32 P6 = cvtpk(p[o + 12], p[o + 13]), P7 = cvtpk(p[o + 14], p[o + 15]);
        u32 Y0 = __shfl_xor(hb ? P0 : P2, 32);
        u32 Y1 = __shfl_xor(hb ? P1 : P3, 32);
        u32 Y2 = __shfl_xor(hb ? P4 : P6, 32);
        u32 Y3 = __shfl_xor(hb ? P5 : P7, 32);
        fr[st * 2 + 0] = __builtin_bit_cast(bf16x8,
            (u32x4){hb ? Y0 : P0, hb ? Y1 : P1, hb ? P2 : Y0, hb ? P3 : Y1});
        fr[st * 2 + 1] = __builtin_bit_cast(bf16x8,
            (u32x4){hb ? Y2 : P4, hb ? Y3 : P5, hb ? P6 : Y2, hb ? P7 : Y3});
      }

      __builtin_amdgcn_s_setprio(1);
      #pragma unroll
      for (int dt = 0; dt < 4; ++dt) {
        const int vrow = (dt * 32 + ql) * 64;
        #pragma unroll
        for (int ks = 0; ks < 4; ++ks) {
          bf16x8 v = *(const bf16x8*)(Vt + vrow + (((2 * ks + hi) ^ (ql & 7)) * 8));
          acc[dt] = __builtin_amdgcn_mfma_f32_32x32x16_bf16(v, fr[ks], acc[dt], 0, 0, 0);
        }
      }
      __builtin_amdgcn_s_setprio(0);
    }
    cur ^= 1;
  }

  __syncthreads();
  u16* Ot = &Ktb[0][0];
  const float inv = 1.f / lsum;
  const int orow = w * 32 + ql;
  #pragma unroll
  for (int dt = 0; dt < 4; ++dt) {
    #pragma unroll
    for (int rq = 0; rq < 4; ++rq) {
      const int dhb = dt * 32 + 8 * rq + 4 * hi;
      const int dhs = dhb ^ ((ql & 15) << 3);
      u16 e0 = f2bf(acc[dt][rq * 4 + 0] * inv);
      u16 e1 = f2bf(acc[dt][rq * 4 + 1] * inv);
      u16 e2 = f2bf(acc[dt][rq * 4 + 2] * inv);
      u16 e3 = f2bf(acc[dt][rq * 4 + 3] * inv);
      u32 w0 = (u32)e0 | ((u32)e1 << 16);
      u32 w1 = (u32)e2 | ((u32)e3 << 16);
      *(u32*)(Ot + orow * 128 + dhs)     = w0;
      *(u32*)(Ot + orow * 128 + dhs + 2) = w1;
    }
  }
  __syncthreads();
  #pragma unroll
  for (int i = 0; i < 8; ++i) {
    const int n = i * 256 + tid;
    const int q = n >> 4, g = n & 15;
    bf16x8 v = *(const bf16x8*)(Ot + q * 128 + ((g ^ (q & 15)) * 8));
    *(bf16x8*)(ctx + ((size_t)b * T + qbase + q) * rs + h * 128 + g * 8) = v;
  }
}

// ---------------- launcher ----------------
extern "C" void kernel_launch(void* const* d_in, const int* in_sizes, int n_in,
                              void* d_out, int out_size, void* d_ws, size_t ws_size,
                              hipStream_t stream)
{
  (void)n_in; (void)out_size; (void)ws_size;
  const float* x   = (const float*)d_in[0];
  const float* qdw = (const float*)d_in[1];
  const float* kdw = (const float*)d_in[2];
  const float* vdw = (const float*)d_in[3];
  const float* quw = (const float*)d_in[4];
  const float* kuw = (const float*)d_in[5];
  const float* vuw = (const float*)d_in[6];
  const float* oww = (const float*)d_in[7];
  const float* ob  = (const float*)d_in[8];

  const int d = 2048, r = 512;
  const int BT = in_sizes[0] / d;   // B*T = 4096

  u16* p = (u16*)d_ws;
  auto take = [&](size_t n) { u16* q = p; p += n; return q; };
  u16* xb  = take((size_t)BT * d);
  u16* wqd = take((size_t)r * d);
  u16* wkd = take((size_t)r * d);
  u16* wvd = take((size_t)r * d);
  u16* wqu = take((size_t)d * r);
  u16* wku = take((size_t)d * r);
  u16* wvu = take((size_t)d * r);
  u16* wow = take((size_t)d * d);
  u16* Qd  = take((size_t)BT * r);
  u16* Kd  = take((size_t)BT * r);
  u16* Vd  = take((size_t)BT * r);
  u16* Qu  = take((size_t)BT * d);
  u16* Ku  = take((size_t)BT * d);
  u16* Vtg = take((size_t)BT * d);   // transposed: [d][BT]
  u16* ctx = take((size_t)BT * d);

  CvtArgs ca;
  const float* ins[8] = {x, oww, qdw, kdw, vdw, quw, kuw, vuw};
  u16* outs[8]        = {xb, wow, wqd, wkd, wvd, wqu, wku, wvu};
  const size_t ns[8]  = {(size_t)BT * d, (size_t)d * d,
                         (size_t)r * d, (size_t)r * d, (size_t)r * d,
                         (size_t)d * r, (size_t)d * r, (size_t)d * r};
  int total_blk = 0;
  for (int t = 0; t < 8; ++t) {
    ca.in[t] = ins[t]; ca.out[t] = outs[t];
    ca.n8[t] = (int)(ns[t] / 8);
    ca.nblk[t] = (ca.n8[t] + 255) / 256;
    total_blk += ca.nblk[t];
  }
  cvt_multi<<<dim3(total_blk), dim3(256), 0, stream>>>(ca);

  // down projections: Qd/Kd/Vd = x @ Wd^T   [BT,2048] -> [BT,512]
  GemmB3 g1;
  g1.A[0] = xb;  g1.A[1] = xb;  g1.A[2] = xb;
  g1.Bm[0] = wqd; g1.Bm[1] = wkd; g1.Bm[2] = wvd;
  g1.C[0] = Qd;  g1.C[1] = Kd;  g1.C[2] = Vd;
  g1.alpha[0] = 1.f; g1.alpha[1] = 1.f; g1.alpha[2] = 1.f;
  g1.Nz[0] = r; g1.Nz[1] = r; g1.Nz[2] = r;
  gemm_bt<false><<<dim3(BT / 128, r / 128, 3), dim3(256), 0, stream>>>(
      g1, nullptr, nullptr, d, -1);

  // up projections, one launch: z0=Qu, z1=Ku, z2=Vtg (transposed, swapped grid)
  GemmB3 g2;
  g2.A[0] = Qd;  g2.A[1] = Kd;  g2.A[2] = wvu;
  g2.Bm[0] = wqu; g2.Bm[1] = wku; g2.Bm[2] = Vd;
  g2.C[0] = Qu;  g2.C[1] = Ku;  g2.C[2] = Vtg;
  g2.alpha[0] = 0.12751743f; g2.alpha[1] = 1.f; g2.alpha[2] = 1.f;
  g2.Nz[0] = d; g2.Nz[1] = d; g2.Nz[2] = BT;
  gemm_bt<false><<<dim3(BT / 128, d / 128, 3), dim3(256), 0, stream>>>(
      g2, nullptr, nullptr, r, 2);

  // flash attention: 16 q-tiles x 32 (b,h), low-bit heavy/light pairing
  mla_attn<<<dim3(512), dim3(256), 0, stream>>>(Qu, Ku, Vtg, ctx);

  // output projection: out = ctx @ out_w^T + out_b (fp32 out)
  GemmB3 g3;
  g3.A[0] = ctx; g3.A[1] = ctx; g3.A[2] = ctx;
  g3.Bm[0] = wow; g3.Bm[1] = wow; g3.Bm[2] = wow;
  g3.C[0] = nullptr; g3.C[1] = nullptr; g3.C[2] = nullptr;
  g3.alpha[0] = 1.f; g3.alpha[1] = 1.f; g3.alpha[2] = 1.f;
  g3.Nz[0] = d; g3.Nz[1] = d; g3.Nz[2] = d;
  gemm_bt<true><<<dim3(BT / 128, d / 128, 1), dim3(256), 0, stream>>>(
      g3, (float*)d_out, ob, d, -1);
}